// Round 15
// baseline (272.090 us; speedup 1.0000x reference)
//
#include <hip/hip_runtime.h>

#define L_SEQ 2048
#define NDIM 2048
#define DINNER 2048
#define NSTATE 32
#define BSZ 4
#define DTR 64
#define NROWS (BSZ * L_SEQ)  // 8192
#define TCH 32               // timesteps per scan chunk
#define LHALF (L_SEQ / 2)    // 1024

typedef short bf16x8 __attribute__((ext_vector_type(8)));
typedef float f32x4 __attribute__((ext_vector_type(4)));
typedef float f32x2 __attribute__((ext_vector_type(2)));
typedef unsigned int uint_t;

#if __has_builtin(__builtin_amdgcn_exp2f)
#define EXP2(v) __builtin_amdgcn_exp2f(v)
#else
#define EXP2(v) exp2f(v)
#endif
#define LOG2E 1.44269504f

__device__ __forceinline__ uint_t bf1(float a) {
  uint_t u = __float_as_uint(a);
  return (u + 0x7FFFu + ((u >> 16) & 1u)) >> 16;
}
__device__ __forceinline__ uint_t pkbf(float a, float b) {
  return bf1(a) | (bf1(b) << 16);
}

// ---------------- Kernel 0: convert W_bc, W_dt to bf16 in ws ----------------
#define WBC_ELEMS (128 * NDIM)
#define WDT_ELEMS (DINNER * DTR)
__global__ __launch_bounds__(256) void k_conv(const float* __restrict__ Wbc,
                                              const float* __restrict__ Wdt,
                                              unsigned short* __restrict__ o) {
  const int i = blockIdx.x * 256 + threadIdx.x;
  if (i < WBC_ELEMS)
    o[i] = (unsigned short)bf1(Wbc[i]);
  else
    o[i] = (unsigned short)bf1(Wdt[i - WBC_ELEMS]);
}

// ------- Kernel 1 (MFMA): deltaBC = x @ W_bc^T (512-thr, 8 waves) --------
__global__ __launch_bounds__(512) void k_dbc_mfma(const float* __restrict__ x,
                                                  const unsigned short* __restrict__ Wb,
                                                  float* __restrict__ dbc) {
  __shared__ unsigned short xl[32][72];
  __shared__ unsigned short wl[128][72];
  const int tid = threadIdx.x;
  const int wave = tid >> 6, lane = tid & 63;
  const int row0 = blockIdx.x * 32;
  const int wrow0 = (wave & 1) * 16;
  const int wcol0 = (wave >> 1) * 32;
  const int fr = lane & 15, fk = (lane >> 4) * 8;

  f32x4 acc[2];
#pragma unroll
  for (int i = 0; i < 2; ++i) acc[i] = (f32x4)(0.f);

  const int xr = tid >> 4, xk = (tid & 15) * 4;   // x staging role
  const int wc = tid & 127, wh = (tid >> 7) * 16; // W staging role

  for (int kb = 0; kb < NDIM; kb += 64) {
    const float4 xa = *(const float4*)(x + (size_t)(row0 + xr) * NDIM + kb + xk);
    uint4 wv0 = *(const uint4*)(Wb + (size_t)wc * NDIM + kb + wh);
    uint4 wv1 = *(const uint4*)(Wb + (size_t)wc * NDIM + kb + wh + 8);
    __syncthreads();
    uint2 xp = {pkbf(xa.x, xa.y), pkbf(xa.z, xa.w)};
    *(uint2*)&xl[xr][xk] = xp;
    *(uint4*)&wl[wc][wh] = wv0;
    *(uint4*)&wl[wc][wh + 8] = wv1;
    __syncthreads();
#pragma unroll
    for (int ks = 0; ks < 2; ++ks) {
      const bf16x8 af = *(const bf16x8*)&xl[wrow0 + fr][ks * 32 + fk];
#pragma unroll
      for (int nt = 0; nt < 2; ++nt) {
        const bf16x8 bfv = *(const bf16x8*)&wl[wcol0 + nt * 16 + fr][ks * 32 + fk];
        acc[nt] = __builtin_amdgcn_mfma_f32_16x16x32_bf16(af, bfv, acc[nt], 0, 0, 0);
      }
    }
  }
#pragma unroll
  for (int nt = 0; nt < 2; ++nt)
#pragma unroll
    for (int reg = 0; reg < 4; ++reg)
      dbc[(size_t)(row0 + wrow0 + (lane >> 4) * 4 + reg) * 128 + wcol0 + nt * 16 + fr] =
          acc[nt][reg];
}

// ------- Kernel 2 (MFMA): delta = softplus(dt_r @ W_dt^T + b) -> dy -------
__global__ __launch_bounds__(256) void k_dt_mfma(const float* __restrict__ dbc,
                                                 const unsigned short* __restrict__ Wd,
                                                 const float* __restrict__ bdt,
                                                 float* __restrict__ dy) {
  __shared__ unsigned short al[32][72];
  const int tid = threadIdx.x;
  const int wave = tid >> 6, lane = tid & 63;
  const int row0 = blockIdx.y * 32;
  const int c0 = blockIdx.x * 256;
  const int wrow0 = (wave & 1) * 16;
  const int wc0 = c0 + (wave >> 1) * 128;
  const int fr = lane & 15, fk = (lane >> 4) * 8;

  {
    const int ar = tid >> 3, ak = (tid & 7) * 8;
    const float4 pa = *(const float4*)(dbc + (size_t)(row0 + ar) * 128 + ak);
    const float4 pb = *(const float4*)(dbc + (size_t)(row0 + ar) * 128 + ak + 4);
    uint4 ap = {pkbf(pa.x, pa.y), pkbf(pa.z, pa.w), pkbf(pb.x, pb.y), pkbf(pb.z, pb.w)};
    *(uint4*)&al[ar][ak] = ap;
  }
  __syncthreads();

  f32x4 acc[8];
#pragma unroll
  for (int i = 0; i < 8; ++i) acc[i] = (f32x4)(0.f);

#pragma unroll
  for (int ks = 0; ks < 2; ++ks) {
    const bf16x8 af = *(const bf16x8*)&al[wrow0 + fr][ks * 32 + fk];
#pragma unroll
    for (int nt = 0; nt < 8; ++nt) {
      const int col = wc0 + nt * 16 + fr;
      const bf16x8 bfv = *(const bf16x8*)(Wd + (size_t)col * 64 + ks * 32 + fk);
      acc[nt] = __builtin_amdgcn_mfma_f32_16x16x32_bf16(af, bfv, acc[nt], 0, 0, 0);
    }
  }

#pragma unroll
  for (int nt = 0; nt < 8; ++nt) {
    const int col = wc0 + nt * 16 + fr;
    const float bias = bdt[col];
#pragma unroll
    for (int reg = 0; reg < 4; ++reg) {
      const float v = acc[nt][reg] + bias;
      const float sp = (v > 20.f) ? v : __logf(1.f + __expf(v));
      dy[(size_t)(row0 + wrow0 + (lane >> 4) * 4 + reg) * DINNER + col] = sp;
    }
  }
}

// ---------------- fp32 fallback GEMMs ----------------
__global__ __launch_bounds__(256) void k_dbc(const float* __restrict__ x,
                                             const float* __restrict__ Wbc,
                                             float* __restrict__ dbc) {
  __shared__ float xs[32][36];
  __shared__ float ws[32][132];
  const int tid = threadIdx.x;
  const int tx = tid & 31;
  const int ty = tid >> 5;
  const int row0 = blockIdx.x * 32;
  float acc[4][4];
#pragma unroll
  for (int i = 0; i < 4; ++i)
#pragma unroll
    for (int j = 0; j < 4; ++j) acc[i][j] = 0.f;
  for (int kb = 0; kb < NDIM; kb += 32) {
    {
      const int r = tid >> 3;
      const int k0 = (tid & 7) * 4;
      const float4 v = *(const float4*)(x + (size_t)(row0 + r) * NDIM + kb + k0);
      *(float4*)&xs[r][k0] = v;
    }
    {
      const int col = tid & 127;
      const int k0 = (tid >> 7) * 16;
#pragma unroll
      for (int j = 0; j < 4; ++j) {
        const float4 v = *(const float4*)(Wbc + (size_t)col * NDIM + kb + k0 + j * 4);
        ws[k0 + j * 4 + 0][col] = v.x;
        ws[k0 + j * 4 + 1][col] = v.y;
        ws[k0 + j * 4 + 2][col] = v.z;
        ws[k0 + j * 4 + 3][col] = v.w;
      }
    }
    __syncthreads();
#pragma unroll
    for (int k = 0; k < 32; k += 4) {
      float a_[4][4];
#pragma unroll
      for (int i = 0; i < 4; ++i) {
        const float4 av = *(const float4*)&xs[ty * 4 + i][k];
        a_[i][0] = av.x; a_[i][1] = av.y; a_[i][2] = av.z; a_[i][3] = av.w;
      }
#pragma unroll
      for (int kk = 0; kk < 4; ++kk) {
        const float4 bv = *(const float4*)&ws[k + kk][tx * 4];
        float b_[4] = {bv.x, bv.y, bv.z, bv.w};
#pragma unroll
        for (int i = 0; i < 4; ++i)
#pragma unroll
          for (int j = 0; j < 4; ++j)
            acc[i][j] = fmaf(a_[i][kk], b_[j], acc[i][j]);
      }
    }
    __syncthreads();
  }
#pragma unroll
  for (int i = 0; i < 4; ++i) {
    float4 o = {acc[i][0], acc[i][1], acc[i][2], acc[i][3]};
    *(float4*)(dbc + (size_t)(row0 + ty * 4 + i) * 128 + tx * 4) = o;
  }
}

__global__ __launch_bounds__(256) void k_dt(const float* __restrict__ dbc,
                                            const float* __restrict__ Wdt,
                                            const float* __restrict__ bdt,
                                            float* dy) {
  __shared__ float asn[16][68];
  __shared__ float wst[64][132];
  const int tid = threadIdx.x;
  const int tx = tid & 31;
  const int ty = tid >> 5;
  const int row0 = blockIdx.y * 16;
  const int col0 = blockIdx.x * 128;
  {
    const int r = tid >> 4;
    const int k0 = (tid & 15) * 4;
    const float4 v = *(const float4*)(dbc + (size_t)(row0 + r) * 128 + k0);
    *(float4*)&asn[r][k0] = v;
  }
  {
    const int col = tid & 127;
    const int k0 = (tid >> 7) * 32;
#pragma unroll
    for (int j = 0; j < 8; ++j) {
      const float4 v = *(const float4*)(Wdt + (size_t)(col0 + col) * 64 + k0 + j * 4);
      wst[k0 + j * 4 + 0][col] = v.x;
      wst[k0 + j * 4 + 1][col] = v.y;
      wst[k0 + j * 4 + 2][col] = v.z;
      wst[k0 + j * 4 + 3][col] = v.w;
    }
  }
  __syncthreads();
  float acc[2][4];
#pragma unroll
  for (int i = 0; i < 2; ++i)
#pragma unroll
    for (int j = 0; j < 4; ++j) acc[i][j] = 0.f;
#pragma unroll
  for (int k = 0; k < 64; k += 4) {
    float a_[2][4];
#pragma unroll
    for (int i = 0; i < 2; ++i) {
      const float4 av = *(const float4*)&asn[ty * 2 + i][k];
      a_[i][0] = av.x; a_[i][1] = av.y; a_[i][2] = av.z; a_[i][3] = av.w;
    }
#pragma unroll
    for (int kk = 0; kk < 4; ++kk) {
      const float4 bv = *(const float4*)&wst[k + kk][tx * 4];
      float b_[4] = {bv.x, bv.y, bv.z, bv.w};
#pragma unroll
      for (int i = 0; i < 2; ++i)
#pragma unroll
        for (int j = 0; j < 4; ++j)
          acc[i][j] = fmaf(a_[i][kk], b_[j], acc[i][j]);
    }
  }
  const int c = col0 + tx * 4;
  const float4 bb = *(const float4*)(bdt + c);
  const float bias[4] = {bb.x, bb.y, bb.z, bb.w};
#pragma unroll
  for (int i = 0; i < 2; ++i) {
    float o[4];
#pragma unroll
    for (int j = 0; j < 4; ++j) {
      const float v = acc[i][j] + bias[j];
      o[j] = (v > 20.f) ? v : __logf(1.f + __expf(v));
    }
    float4 ov = {o[0], o[1], o[2], o[3]};
    *(float4*)(dy + (size_t)(row0 + ty * 2 + i) * DINNER + c) = ov;
  }
}

// ---------------- scan primitives ----------------
template <int CTRL>
__device__ __forceinline__ float dpp_mov(float v) {
  return __int_as_float(
      __builtin_amdgcn_update_dpp(0, __float_as_int(v), CTRL, 0xF, 0xF, true));
}
// full sum over each 16-lane row (4 DPP stages)
__device__ __forceinline__ float red16(float p) {
  p += dpp_mov<0xB1>(p);
  p += dpp_mov<0x4E>(p);
  p += dpp_mov<0x141>(p);
  p += dpp_mov<0x140>(p);
  return p;
}

// ---- Pass 1 (packed, h-only): scan first half, write h_end --------------
// 256 thr = 16 channels x 16 lanes (2 states/lane); grid 512.
__global__ __launch_bounds__(256) void k_p1p(const float* __restrict__ x,
                                             const float* __restrict__ dlt,
                                             const float* __restrict__ dbc,
                                             const float* __restrict__ Alog,
                                             float* __restrict__ hbuf) {
  __shared__ float sDU[2][16][68];  // [buf][ch][t2*4 + {d,du,d',d'u'}]
  __shared__ float sBp[2][32][34];  // [buf][t][ln*2 + {B0,B1}]

  const int tid = threadIdx.x;
  const int ln = tid & 15, ch = tid >> 4;  // compute role
  const int dd = tid & 15, tl = tid >> 4;  // DU staging role (t=tl, tl+16)
  const int nb = tid & 31, tq = tid >> 5;  // B staging role (t=tq+{0,8,16,24})
  const int dg = blockIdx.x & 127;
  const int b = blockIdx.x >> 7;
  const int d0 = dg * 16;
  const int NCHK = LHALF / TCH;  // 32

  f32x2 An2;
  An2.x = -__expf(Alog[(size_t)(d0 + ch) * NSTATE + ln]) * LOG2E;
  An2.y = -__expf(Alog[(size_t)(d0 + ch) * NSTATE + ln + 16]) * LOG2E;
  const size_t segbase = (size_t)b * L_SEQ;
  const int bcol = (nb & 15) * 2 + (nb >> 4);

  {  // prologue: stage chunk 0
    const size_t rX0 = (segbase + tl) * DINNER + d0 + dd;
    const size_t rX1 = (segbase + tl + 16) * DINNER + d0 + dd;
    const float dv0 = dlt[rX0], uv0 = x[rX0];
    const float dv1 = dlt[rX1], uv1 = x[rX1];
    *(float2*)&sDU[0][dd][(tl >> 1) * 4 + (tl & 1) * 2] = make_float2(dv0, dv0 * uv0);
    *(float2*)&sDU[0][dd][((tl + 16) >> 1) * 4 + (tl & 1) * 2] =
        make_float2(dv1, dv1 * uv1);
#pragma unroll
    for (int k = 0; k < 4; ++k) {
      const int t = tq + k * 8;
      sBp[0][t][bcol] = dbc[(segbase + t) * 128 + 64 + nb];
    }
  }
  __syncthreads();

  f32x2 h = (f32x2)(0.f);
  for (int c = 0; c < NCHK; ++c) {
    const int cb = c & 1;
    float dn0 = 0.f, un0 = 0.f, dn1 = 0.f, un1 = 0.f;
    float bnx[4] = {0.f, 0.f, 0.f, 0.f};
    if (c < NCHK - 1) {
      const size_t rX0 = (segbase + (c + 1) * TCH + tl) * DINNER + d0 + dd;
      const size_t rX1 = (segbase + (c + 1) * TCH + tl + 16) * DINNER + d0 + dd;
      dn0 = dlt[rX0];
      un0 = x[rX0];
      dn1 = dlt[rX1];
      un1 = x[rX1];
#pragma unroll
      for (int k = 0; k < 4; ++k)
        bnx[k] = dbc[(segbase + (c + 1) * TCH + tq + k * 8) * 128 + 64 + nb];
    }

    const float* pDU = &sDU[cb][ch][0];
    const float* pBp = &sBp[cb][0][ln * 2];
#pragma unroll
    for (int t2 = 0; t2 < TCH / 2; ++t2) {
      const float4 du = *(const float4*)(pDU + t2 * 4);
      const float2 b0 = *(const float2*)(pBp + (2 * t2) * 34);
      const float2 b1 = *(const float2*)(pBp + (2 * t2 + 1) * 34);
      {
        f32x2 ea = An2 * du.x;
        f32x2 dA;
        dA.x = EXP2(ea.x);
        dA.y = EXP2(ea.y);
        f32x2 Bp;
        Bp.x = b0.x;
        Bp.y = b0.y;
        h = dA * h + Bp * du.y;
      }
      {
        f32x2 ea = An2 * du.z;
        f32x2 dA;
        dA.x = EXP2(ea.x);
        dA.y = EXP2(ea.y);
        f32x2 Bp;
        Bp.x = b1.x;
        Bp.y = b1.y;
        h = dA * h + Bp * du.w;
      }
    }

    if (c < NCHK - 1) {
      *(float2*)&sDU[cb ^ 1][dd][(tl >> 1) * 4 + (tl & 1) * 2] =
          make_float2(dn0, dn0 * un0);
      *(float2*)&sDU[cb ^ 1][dd][((tl + 16) >> 1) * 4 + (tl & 1) * 2] =
          make_float2(dn1, dn1 * un1);
#pragma unroll
      for (int k = 0; k < 4; ++k) sBp[cb ^ 1][tq + k * 8][bcol] = bnx[k];
    }
    __syncthreads();
  }

  const size_t hb = ((size_t)b * DINNER + d0 + ch) * NSTATE;
  hbuf[hb + ln] = h.x;
  hbuf[hb + ln + 16] = h.y;
}

// ---- Pass 2 (packed, full): y over one half-sequence, h_in from hbuf -----
template <int SEG>
__device__ __forceinline__ void scanp_body(const float* __restrict__ x,
                                           const float* __restrict__ dbc,
                                           const float* __restrict__ Alog,
                                           const float* __restrict__ Dpar,
                                           const float* __restrict__ hbuf,
                                           float* __restrict__ dy, int bid,
                                           float (*sDU)[16][68],
                                           float (*sBCp)[32][68],
                                           float (*sY)[32][17]) {
  const int tid = threadIdx.x;
  const int ln = tid & 15, ch = tid >> 4;  // compute role
  const int dd = tid & 15, tl = tid >> 4;  // DU staging + store role
  const int nb = tid & 31, tq = tid >> 5;  // BC staging role
  const int dg = bid & 127;
  const int b = bid >> 7;
  const int d0 = dg * 16;
  const int NCHK = LHALF / TCH;  // 32

  f32x2 An2;
  An2.x = -__expf(Alog[(size_t)(d0 + ch) * NSTATE + ln]) * LOG2E;
  An2.y = -__expf(Alog[(size_t)(d0 + ch) * NSTATE + ln + 16]) * LOG2E;
  const float Dd = Dpar[d0 + dd];
  const size_t segbase = (size_t)b * L_SEQ + SEG * LHALF;
  const int bccol = (nb & 15) * 4 + (nb >> 4) * 2;

  float u0, u1;
  {  // prologue: stage chunk 0
    const size_t rX0 = (segbase + tl) * DINNER + d0 + dd;
    const size_t rX1 = (segbase + tl + 16) * DINNER + d0 + dd;
    const float dv0 = dy[rX0], uv0 = x[rX0];
    const float dv1 = dy[rX1], uv1 = x[rX1];
    *(float2*)&sDU[0][dd][(tl >> 1) * 4 + (tl & 1) * 2] = make_float2(dv0, dv0 * uv0);
    *(float2*)&sDU[0][dd][((tl + 16) >> 1) * 4 + (tl & 1) * 2] =
        make_float2(dv1, dv1 * uv1);
    u0 = uv0;
    u1 = uv1;
#pragma unroll
    for (int k = 0; k < 4; ++k) {
      const int t = tq + k * 8;
      const size_t rB = (segbase + t) * 128 + 64 + nb;
      *(float2*)&sBCp[0][t][bccol] = make_float2(dbc[rB], dbc[rB + 32]);
    }
  }

  f32x2 h = (f32x2)(0.f);
  if (SEG == 1) {
    const size_t hb = ((size_t)b * DINNER + d0 + ch) * NSTATE;
    h.x = hbuf[hb + ln];
    h.y = hbuf[hb + ln + 16];
  }
  __syncthreads();

  for (int c = 0; c < NCHK; ++c) {
    const int cb = c & 1;
    float dn0 = 0.f, un0 = 0.f, dn1 = 0.f, un1 = 0.f;
    float2 bcx[4];
#pragma unroll
    for (int k = 0; k < 4; ++k) bcx[k] = make_float2(0.f, 0.f);
    if (c < NCHK - 1) {
      const size_t rX0 = (segbase + (c + 1) * TCH + tl) * DINNER + d0 + dd;
      const size_t rX1 = (segbase + (c + 1) * TCH + tl + 16) * DINNER + d0 + dd;
      dn0 = dy[rX0];
      un0 = x[rX0];
      dn1 = dy[rX1];
      un1 = x[rX1];
#pragma unroll
      for (int k = 0; k < 4; ++k) {
        const size_t rB = (segbase + (c + 1) * TCH + tq + k * 8) * 128 + 64 + nb;
        bcx[k] = make_float2(dbc[rB], dbc[rB + 32]);
      }
    }

    const float* pDU = &sDU[cb][ch][0];
    const float* pBC = &sBCp[cb][0][ln * 4];
    float yv0 = 0.f, yv1 = 0.f;
#pragma unroll
    for (int t2 = 0; t2 < TCH / 2; ++t2) {
      const float4 du = *(const float4*)(pDU + t2 * 4);
      const float4 b0 = *(const float4*)(pBC + (2 * t2) * 68);
      const float4 b1 = *(const float4*)(pBC + (2 * t2 + 1) * 68);
      {
        const int t = 2 * t2;
        f32x2 ea = An2 * du.x;
        f32x2 dA;
        dA.x = EXP2(ea.x);
        dA.y = EXP2(ea.y);
        f32x2 Bp;
        Bp.x = b0.x;
        Bp.y = b0.z;
        f32x2 Cp;
        Cp.x = b0.y;
        Cp.y = b0.w;
        h = dA * h + Bp * du.y;
        const f32x2 pp = h * Cp;
        const float p = red16(pp.x + pp.y);
        if (t < 16)
          yv0 = (ln == t) ? p : yv0;
        else
          yv1 = (ln == t - 16) ? p : yv1;
      }
      {
        const int t = 2 * t2 + 1;
        f32x2 ea = An2 * du.z;
        f32x2 dA;
        dA.x = EXP2(ea.x);
        dA.y = EXP2(ea.y);
        f32x2 Bp;
        Bp.x = b1.x;
        Bp.y = b1.z;
        f32x2 Cp;
        Cp.x = b1.y;
        Cp.y = b1.w;
        h = dA * h + Bp * du.w;
        const f32x2 pp = h * Cp;
        const float p = red16(pp.x + pp.y);
        if (t < 16)
          yv0 = (ln == t) ? p : yv0;
        else
          yv1 = (ln == t - 16) ? p : yv1;
      }
    }
    sY[cb][ln][ch] = yv0;
    sY[cb][ln + 16][ch] = yv1;

    if (c < NCHK - 1) {
      *(float2*)&sDU[cb ^ 1][dd][(tl >> 1) * 4 + (tl & 1) * 2] =
          make_float2(dn0, dn0 * un0);
      *(float2*)&sDU[cb ^ 1][dd][((tl + 16) >> 1) * 4 + (tl & 1) * 2] =
          make_float2(dn1, dn1 * un1);
#pragma unroll
      for (int k = 0; k < 4; ++k)
        *(float2*)&sBCp[cb ^ 1][tq + k * 8][bccol] = bcx[k];
    }
    __syncthreads();

    dy[(segbase + c * TCH + tl) * DINNER + d0 + dd] = fmaf(u0, Dd, sY[cb][tl][dd]);
    dy[(segbase + c * TCH + tl + 16) * DINNER + d0 + dd] =
        fmaf(u1, Dd, sY[cb][tl + 16][dd]);
    u0 = un0;
    u1 = un1;
  }
}

__global__ __launch_bounds__(256) void k_p2p(const float* __restrict__ x,
                                             const float* __restrict__ dbc,
                                             const float* __restrict__ Alog,
                                             const float* __restrict__ Dpar,
                                             const float* __restrict__ hbuf,
                                             float* __restrict__ dy) {
  __shared__ float sDU[2][16][68];
  __shared__ float sBCp[2][32][68];
  __shared__ float sY[2][32][17];
  const int bx = blockIdx.x;
  if (bx < BSZ * DINNER / 16)
    scanp_body<0>(x, dbc, Alog, Dpar, hbuf, dy, bx, sDU, sBCp, sY);
  else
    scanp_body<1>(x, dbc, Alog, Dpar, hbuf, dy, bx - BSZ * DINNER / 16, sDU,
                  sBCp, sY);
}

// ---- fallback: monolithic packed scan (R13 proven, 203.9 us) -------------
__global__ __launch_bounds__(256) void k_scanp(const float* __restrict__ x,
                                               const float* __restrict__ dbc,
                                               const float* __restrict__ Alog,
                                               const float* __restrict__ Dpar,
                                               float* __restrict__ dy) {
  __shared__ float sDU[2][16][68];
  __shared__ float sBCp[2][32][68];
  __shared__ float sY[2][32][17];

  const int tid = threadIdx.x;
  const int ln = tid & 15, ch = tid >> 4;
  const int dd = tid & 15, tl = tid >> 4;
  const int nb = tid & 31, tq = tid >> 5;
  const int dg = blockIdx.x & 127;
  const int b = blockIdx.x >> 7;
  const int d0 = dg * 16;
  const int NCHK = L_SEQ / TCH;

  f32x2 An2;
  An2.x = -__expf(Alog[(size_t)(d0 + ch) * NSTATE + ln]) * LOG2E;
  An2.y = -__expf(Alog[(size_t)(d0 + ch) * NSTATE + ln + 16]) * LOG2E;
  const float Dd = Dpar[d0 + dd];
  const size_t segbase = (size_t)b * L_SEQ;
  const int bccol = (nb & 15) * 4 + (nb >> 4) * 2;

  float u0, u1;
  {
    const size_t rX0 = (segbase + tl) * DINNER + d0 + dd;
    const size_t rX1 = (segbase + tl + 16) * DINNER + d0 + dd;
    const float dv0 = dy[rX0], uv0 = x[rX0];
    const float dv1 = dy[rX1], uv1 = x[rX1];
    *(float2*)&sDU[0][dd][(tl >> 1) * 4 + (tl & 1) * 2] = make_float2(dv0, dv0 * uv0);
    *(float2*)&sDU[0][dd][((tl + 16) >> 1) * 4 + (tl & 1) * 2] =
        make_float2(dv1, dv1 * uv1);
    u0 = uv0;
    u1 = uv1;
#pragma unroll
    for (int k = 0; k < 4; ++k) {
      const int t = tq + k * 8;
      const size_t rB = (segbase + t) * 128 + 64 + nb;
      *(float2*)&sBCp[0][t][bccol] = make_float2(dbc[rB], dbc[rB + 32]);
    }
  }
  __syncthreads();

  f32x2 h = (f32x2)(0.f);
  for (int c = 0; c < NCHK; ++c) {
    const int cb = c & 1;
    float dn0 = 0.f, un0 = 0.f, dn1 = 0.f, un1 = 0.f;
    float2 bcx[4];
#pragma unroll
    for (int k = 0; k < 4; ++k) bcx[k] = make_float2(0.f, 0.f);
    if (c < NCHK - 1) {
      const size_t rX0 = (segbase + (c + 1) * TCH + tl) * DINNER + d0 + dd;
      const size_t rX1 = (segbase + (c + 1) * TCH + tl + 16) * DINNER + d0 + dd;
      dn0 = dy[rX0];
      un0 = x[rX0];
      dn1 = dy[rX1];
      un1 = x[rX1];
#pragma unroll
      for (int k = 0; k < 4; ++k) {
        const size_t rB = (segbase + (c + 1) * TCH + tq + k * 8) * 128 + 64 + nb;
        bcx[k] = make_float2(dbc[rB], dbc[rB + 32]);
      }
    }

    const float* pDU = &sDU[cb][ch][0];
    const float* pBC = &sBCp[cb][0][ln * 4];
    float yv0 = 0.f, yv1 = 0.f;
#pragma unroll
    for (int t2 = 0; t2 < TCH / 2; ++t2) {
      const float4 du = *(const float4*)(pDU + t2 * 4);
      const float4 b0 = *(const float4*)(pBC + (2 * t2) * 68);
      const float4 b1 = *(const float4*)(pBC + (2 * t2 + 1) * 68);
      {
        const int t = 2 * t2;
        f32x2 ea = An2 * du.x;
        f32x2 dA;
        dA.x = EXP2(ea.x);
        dA.y = EXP2(ea.y);
        f32x2 Bp;
        Bp.x = b0.x;
        Bp.y = b0.z;
        f32x2 Cp;
        Cp.x = b0.y;
        Cp.y = b0.w;
        h = dA * h + Bp * du.y;
        const f32x2 pp = h * Cp;
        const float p = red16(pp.x + pp.y);
        if (t < 16)
          yv0 = (ln == t) ? p : yv0;
        else
          yv1 = (ln == t - 16) ? p : yv1;
      }
      {
        const int t = 2 * t2 + 1;
        f32x2 ea = An2 * du.z;
        f32x2 dA;
        dA.x = EXP2(ea.x);
        dA.y = EXP2(ea.y);
        f32x2 Bp;
        Bp.x = b1.x;
        Bp.y = b1.z;
        f32x2 Cp;
        Cp.x = b1.y;
        Cp.y = b1.w;
        h = dA * h + Bp * du.w;
        const f32x2 pp = h * Cp;
        const float p = red16(pp.x + pp.y);
        if (t < 16)
          yv0 = (ln == t) ? p : yv0;
        else
          yv1 = (ln == t - 16) ? p : yv1;
      }
    }
    sY[cb][ln][ch] = yv0;
    sY[cb][ln + 16][ch] = yv1;

    if (c < NCHK - 1) {
      *(float2*)&sDU[cb ^ 1][dd][(tl >> 1) * 4 + (tl & 1) * 2] =
          make_float2(dn0, dn0 * un0);
      *(float2*)&sDU[cb ^ 1][dd][((tl + 16) >> 1) * 4 + (tl & 1) * 2] =
          make_float2(dn1, dn1 * un1);
#pragma unroll
      for (int k = 0; k < 4; ++k)
        *(float2*)&sBCp[cb ^ 1][tq + k * 8][bccol] = bcx[k];
    }
    __syncthreads();

    dy[(segbase + c * TCH + tl) * DINNER + d0 + dd] = fmaf(u0, Dd, sY[cb][tl][dd]);
    dy[(segbase + c * TCH + tl + 16) * DINNER + d0 + dd] =
        fmaf(u1, Dd, sY[cb][tl + 16][dd]);
    u0 = un0;
    u1 = un1;
  }
}

extern "C" void kernel_launch(void* const* d_in, const int* in_sizes, int n_in,
                              void* d_out, int out_size, void* d_ws, size_t ws_size,
                              hipStream_t stream) {
  const float* x    = (const float*)d_in[0];
  const float* Wbc  = (const float*)d_in[2];
  const float* Wdt  = (const float*)d_in[3];
  const float* bdt  = (const float*)d_in[4];
  const float* Alog = (const float*)d_in[5];
  const float* Dpar = (const float*)d_in[6];
  float* dy  = (float*)d_out;
  float* dbc = (float*)d_ws;  // 4 MiB

  const size_t DBC_BYTES = (size_t)NROWS * 128 * 4;               // 4 MiB
  const size_t WCONV_BYTES = (size_t)(WBC_ELEMS + WDT_ELEMS) * 2; // 768 KiB
  const size_t H_OFF = 8u << 20;                                  // 8 MiB
  const size_t H_BYTES = (size_t)BSZ * DINNER * NSTATE * 4;       // 1 MiB

  const bool mfma_ok = ws_size >= DBC_BYTES + WCONV_BYTES;
  const bool seg_ok = ws_size >= H_OFF + H_BYTES;

  if (mfma_ok) {
    unsigned short* Wb = (unsigned short*)((char*)d_ws + DBC_BYTES);
    unsigned short* Wd = Wb + WBC_ELEMS;
    hipLaunchKernelGGL(k_conv, dim3((WBC_ELEMS + WDT_ELEMS) / 256), dim3(256), 0,
                       stream, Wbc, Wdt, Wb);
    hipLaunchKernelGGL(k_dbc_mfma, dim3(NROWS / 32), dim3(512), 0, stream,
                       x, Wb, dbc);
    hipLaunchKernelGGL(k_dt_mfma, dim3(DINNER / 256, NROWS / 32), dim3(256), 0,
                       stream, dbc, Wd, bdt, dy);
  } else {
    hipLaunchKernelGGL(k_dbc, dim3(NROWS / 32), dim3(256), 0, stream, x, Wbc, dbc);
    hipLaunchKernelGGL(k_dt, dim3(DINNER / 128, NROWS / 16), dim3(256), 0, stream,
                       dbc, Wdt, bdt, dy);
  }

  if (seg_ok) {
    float* hbuf = (float*)((char*)d_ws + H_OFF);
    hipLaunchKernelGGL(k_p1p, dim3(BSZ * DINNER / 16), dim3(256), 0, stream,
                       x, dy, dbc, Alog, hbuf);
    hipLaunchKernelGGL(k_p2p, dim3(2 * BSZ * DINNER / 16), dim3(256), 0, stream,
                       x, dbc, Alog, Dpar, hbuf, dy);
  } else {
    hipLaunchKernelGGL(k_scanp, dim3(BSZ * DINNER / 16), dim3(256), 0, stream,
                       x, dbc, Alog, Dpar, dy);
  }
}

// Round 16
// 246.415 us; speedup vs baseline: 1.1042x; 1.1042x over previous
//
#include <hip/hip_runtime.h>

#define L_SEQ 2048
#define NDIM 2048
#define DINNER 2048
#define NSTATE 32
#define BSZ 4
#define DTR 64
#define NROWS (BSZ * L_SEQ)  // 8192
#define TCH 64               // timesteps per scan chunk (doubled from R13)

typedef short bf16x8 __attribute__((ext_vector_type(8)));
typedef float f32x4 __attribute__((ext_vector_type(4)));
typedef float f32x2 __attribute__((ext_vector_type(2)));
typedef unsigned int uint_t;

#if __has_builtin(__builtin_amdgcn_exp2f)
#define EXP2(v) __builtin_amdgcn_exp2f(v)
#else
#define EXP2(v) exp2f(v)
#endif
#define LOG2E 1.44269504f

__device__ __forceinline__ uint_t bf1(float a) {
  uint_t u = __float_as_uint(a);
  return (u + 0x7FFFu + ((u >> 16) & 1u)) >> 16;
}
__device__ __forceinline__ uint_t pkbf(float a, float b) {
  return bf1(a) | (bf1(b) << 16);
}

// ---------------- Kernel 0: convert W_bc, W_dt to bf16 in ws ----------------
#define WBC_ELEMS (128 * NDIM)
#define WDT_ELEMS (DINNER * DTR)
__global__ __launch_bounds__(256) void k_conv(const float* __restrict__ Wbc,
                                              const float* __restrict__ Wdt,
                                              unsigned short* __restrict__ o) {
  const int i = blockIdx.x * 256 + threadIdx.x;
  if (i < WBC_ELEMS)
    o[i] = (unsigned short)bf1(Wbc[i]);
  else
    o[i] = (unsigned short)bf1(Wdt[i - WBC_ELEMS]);
}

// ------- Kernel 1 (MFMA): deltaBC = x @ W_bc^T (512-thr, 8 waves) --------
__global__ __launch_bounds__(512) void k_dbc_mfma(const float* __restrict__ x,
                                                  const unsigned short* __restrict__ Wb,
                                                  float* __restrict__ dbc) {
  __shared__ unsigned short xl[32][72];
  __shared__ unsigned short wl[128][72];
  const int tid = threadIdx.x;
  const int wave = tid >> 6, lane = tid & 63;
  const int row0 = blockIdx.x * 32;
  const int wrow0 = (wave & 1) * 16;
  const int wcol0 = (wave >> 1) * 32;
  const int fr = lane & 15, fk = (lane >> 4) * 8;

  f32x4 acc[2];
#pragma unroll
  for (int i = 0; i < 2; ++i) acc[i] = (f32x4)(0.f);

  const int xr = tid >> 4, xk = (tid & 15) * 4;   // x staging role
  const int wc = tid & 127, wh = (tid >> 7) * 16; // W staging role

  for (int kb = 0; kb < NDIM; kb += 64) {
    const float4 xa = *(const float4*)(x + (size_t)(row0 + xr) * NDIM + kb + xk);
    uint4 wv0 = *(const uint4*)(Wb + (size_t)wc * NDIM + kb + wh);
    uint4 wv1 = *(const uint4*)(Wb + (size_t)wc * NDIM + kb + wh + 8);
    __syncthreads();
    uint2 xp = {pkbf(xa.x, xa.y), pkbf(xa.z, xa.w)};
    *(uint2*)&xl[xr][xk] = xp;
    *(uint4*)&wl[wc][wh] = wv0;
    *(uint4*)&wl[wc][wh + 8] = wv1;
    __syncthreads();
#pragma unroll
    for (int ks = 0; ks < 2; ++ks) {
      const bf16x8 af = *(const bf16x8*)&xl[wrow0 + fr][ks * 32 + fk];
#pragma unroll
      for (int nt = 0; nt < 2; ++nt) {
        const bf16x8 bfv = *(const bf16x8*)&wl[wcol0 + nt * 16 + fr][ks * 32 + fk];
        acc[nt] = __builtin_amdgcn_mfma_f32_16x16x32_bf16(af, bfv, acc[nt], 0, 0, 0);
      }
    }
  }
#pragma unroll
  for (int nt = 0; nt < 2; ++nt)
#pragma unroll
    for (int reg = 0; reg < 4; ++reg)
      dbc[(size_t)(row0 + wrow0 + (lane >> 4) * 4 + reg) * 128 + wcol0 + nt * 16 + fr] =
          acc[nt][reg];
}

// ------- Kernel 2 (MFMA): delta = softplus(dt_r @ W_dt^T + b) -> dy -------
__global__ __launch_bounds__(256) void k_dt_mfma(const float* __restrict__ dbc,
                                                 const unsigned short* __restrict__ Wd,
                                                 const float* __restrict__ bdt,
                                                 float* __restrict__ dy) {
  __shared__ unsigned short al[32][72];
  const int tid = threadIdx.x;
  const int wave = tid >> 6, lane = tid & 63;
  const int row0 = blockIdx.y * 32;
  const int c0 = blockIdx.x * 256;
  const int wrow0 = (wave & 1) * 16;
  const int wc0 = c0 + (wave >> 1) * 128;
  const int fr = lane & 15, fk = (lane >> 4) * 8;

  {
    const int ar = tid >> 3, ak = (tid & 7) * 8;
    const float4 pa = *(const float4*)(dbc + (size_t)(row0 + ar) * 128 + ak);
    const float4 pb = *(const float4*)(dbc + (size_t)(row0 + ar) * 128 + ak + 4);
    uint4 ap = {pkbf(pa.x, pa.y), pkbf(pa.z, pa.w), pkbf(pb.x, pb.y), pkbf(pb.z, pb.w)};
    *(uint4*)&al[ar][ak] = ap;
  }
  __syncthreads();

  f32x4 acc[8];
#pragma unroll
  for (int i = 0; i < 8; ++i) acc[i] = (f32x4)(0.f);

#pragma unroll
  for (int ks = 0; ks < 2; ++ks) {
    const bf16x8 af = *(const bf16x8*)&al[wrow0 + fr][ks * 32 + fk];
#pragma unroll
    for (int nt = 0; nt < 8; ++nt) {
      const int col = wc0 + nt * 16 + fr;
      const bf16x8 bfv = *(const bf16x8*)(Wd + (size_t)col * 64 + ks * 32 + fk);
      acc[nt] = __builtin_amdgcn_mfma_f32_16x16x32_bf16(af, bfv, acc[nt], 0, 0, 0);
    }
  }

#pragma unroll
  for (int nt = 0; nt < 8; ++nt) {
    const int col = wc0 + nt * 16 + fr;
    const float bias = bdt[col];
#pragma unroll
    for (int reg = 0; reg < 4; ++reg) {
      const float v = acc[nt][reg] + bias;
      const float sp = (v > 20.f) ? v : __logf(1.f + __expf(v));
      dy[(size_t)(row0 + wrow0 + (lane >> 4) * 4 + reg) * DINNER + col] = sp;
    }
  }
}

// ---------------- fp32 fallback GEMMs ----------------
__global__ __launch_bounds__(256) void k_dbc(const float* __restrict__ x,
                                             const float* __restrict__ Wbc,
                                             float* __restrict__ dbc) {
  __shared__ float xs[32][36];
  __shared__ float ws[32][132];
  const int tid = threadIdx.x;
  const int tx = tid & 31;
  const int ty = tid >> 5;
  const int row0 = blockIdx.x * 32;
  float acc[4][4];
#pragma unroll
  for (int i = 0; i < 4; ++i)
#pragma unroll
    for (int j = 0; j < 4; ++j) acc[i][j] = 0.f;
  for (int kb = 0; kb < NDIM; kb += 32) {
    {
      const int r = tid >> 3;
      const int k0 = (tid & 7) * 4;
      const float4 v = *(const float4*)(x + (size_t)(row0 + r) * NDIM + kb + k0);
      *(float4*)&xs[r][k0] = v;
    }
    {
      const int col = tid & 127;
      const int k0 = (tid >> 7) * 16;
#pragma unroll
      for (int j = 0; j < 4; ++j) {
        const float4 v = *(const float4*)(Wbc + (size_t)col * NDIM + kb + k0 + j * 4);
        ws[k0 + j * 4 + 0][col] = v.x;
        ws[k0 + j * 4 + 1][col] = v.y;
        ws[k0 + j * 4 + 2][col] = v.z;
        ws[k0 + j * 4 + 3][col] = v.w;
      }
    }
    __syncthreads();
#pragma unroll
    for (int k = 0; k < 32; k += 4) {
      float a_[4][4];
#pragma unroll
      for (int i = 0; i < 4; ++i) {
        const float4 av = *(const float4*)&xs[ty * 4 + i][k];
        a_[i][0] = av.x; a_[i][1] = av.y; a_[i][2] = av.z; a_[i][3] = av.w;
      }
#pragma unroll
      for (int kk = 0; kk < 4; ++kk) {
        const float4 bv = *(const float4*)&ws[k + kk][tx * 4];
        float b_[4] = {bv.x, bv.y, bv.z, bv.w};
#pragma unroll
        for (int i = 0; i < 4; ++i)
#pragma unroll
          for (int j = 0; j < 4; ++j)
            acc[i][j] = fmaf(a_[i][kk], b_[j], acc[i][j]);
      }
    }
    __syncthreads();
  }
#pragma unroll
  for (int i = 0; i < 4; ++i) {
    float4 o = {acc[i][0], acc[i][1], acc[i][2], acc[i][3]};
    *(float4*)(dbc + (size_t)(row0 + ty * 4 + i) * 128 + tx * 4) = o;
  }
}

__global__ __launch_bounds__(256) void k_dt(const float* __restrict__ dbc,
                                            const float* __restrict__ Wdt,
                                            const float* __restrict__ bdt,
                                            float* dy) {
  __shared__ float asn[16][68];
  __shared__ float wst[64][132];
  const int tid = threadIdx.x;
  const int tx = tid & 31;
  const int ty = tid >> 5;
  const int row0 = blockIdx.y * 16;
  const int col0 = blockIdx.x * 128;
  {
    const int r = tid >> 4;
    const int k0 = (tid & 15) * 4;
    const float4 v = *(const float4*)(dbc + (size_t)(row0 + r) * 128 + k0);
    *(float4*)&asn[r][k0] = v;
  }
  {
    const int col = tid & 127;
    const int k0 = (tid >> 7) * 32;
#pragma unroll
    for (int j = 0; j < 8; ++j) {
      const float4 v = *(const float4*)(Wdt + (size_t)(col0 + col) * 64 + k0 + j * 4);
      wst[k0 + j * 4 + 0][col] = v.x;
      wst[k0 + j * 4 + 1][col] = v.y;
      wst[k0 + j * 4 + 2][col] = v.z;
      wst[k0 + j * 4 + 3][col] = v.w;
    }
  }
  __syncthreads();
  float acc[2][4];
#pragma unroll
  for (int i = 0; i < 2; ++i)
#pragma unroll
    for (int j = 0; j < 4; ++j) acc[i][j] = 0.f;
#pragma unroll
  for (int k = 0; k < 64; k += 4) {
    float a_[2][4];
#pragma unroll
    for (int i = 0; i < 2; ++i) {
      const float4 av = *(const float4*)&asn[ty * 2 + i][k];
      a_[i][0] = av.x; a_[i][1] = av.y; a_[i][2] = av.z; a_[i][3] = av.w;
    }
#pragma unroll
    for (int kk = 0; kk < 4; ++kk) {
      const float4 bv = *(const float4*)&wst[k + kk][tx * 4];
      float b_[4] = {bv.x, bv.y, bv.z, bv.w};
#pragma unroll
      for (int i = 0; i < 2; ++i)
#pragma unroll
        for (int j = 0; j < 4; ++j)
          acc[i][j] = fmaf(a_[i][kk], b_[j], acc[i][j]);
    }
  }
  const int c = col0 + tx * 4;
  const float4 bb = *(const float4*)(bdt + c);
  const float bias[4] = {bb.x, bb.y, bb.z, bb.w};
#pragma unroll
  for (int i = 0; i < 2; ++i) {
    float o[4];
#pragma unroll
    for (int j = 0; j < 4; ++j) {
      const float v = acc[i][j] + bias[j];
      o[j] = (v > 20.f) ? v : __logf(1.f + __expf(v));
    }
    float4 ov = {o[0], o[1], o[2], o[3]};
    *(float4*)(dy + (size_t)(row0 + ty * 2 + i) * DINNER + c) = ov;
  }
}

// ---------------- scan primitives ----------------
template <int CTRL>
__device__ __forceinline__ float dpp_mov(float v) {
  return __int_as_float(
      __builtin_amdgcn_update_dpp(0, __float_as_int(v), CTRL, 0xF, 0xF, true));
}
// full sum over each 16-lane row (4 DPP stages)
__device__ __forceinline__ float red16(float p) {
  p += dpp_mov<0xB1>(p);
  p += dpp_mov<0x4E>(p);
  p += dpp_mov<0x141>(p);
  p += dpp_mov<0x140>(p);
  return p;
}

// ---- Monolithic packed scan (R13 structure), TCH=64: half the barriers ----
// 256 thr = 16 channels x 16 lanes; lane ln holds states {ln, ln+16}.
__global__ __launch_bounds__(256) void k_scanp(const float* __restrict__ x,
                                               const float* __restrict__ dbc,
                                               const float* __restrict__ Alog,
                                               const float* __restrict__ Dpar,
                                               float* __restrict__ dy) {
  __shared__ float sDU[2][16][132];  // [buf][ch][t2*4 + parity*2 + {d,du}], t2<32
  __shared__ float sBCp[2][64][68];  // [buf][t][ln*4 + {B0,C0,B1,C1}]
  __shared__ float sY[2][64][17];    // [buf][t][ch]

  const int tid = threadIdx.x;
  const int ln = tid & 15, ch = tid >> 4;  // compute role
  const int dd = tid & 15, tl = tid >> 4;  // DU staging + store role (t=tl+16k)
  const int nb = tid & 31, tq = tid >> 5;  // BC staging role (t=tq+8k)
  const int dg = blockIdx.x & 127;
  const int b = blockIdx.x >> 7;
  const int d0 = dg * 16;
  const int NCHK = L_SEQ / TCH;  // 32

  f32x2 An2;
  An2.x = -__expf(Alog[(size_t)(d0 + ch) * NSTATE + ln]) * LOG2E;
  An2.y = -__expf(Alog[(size_t)(d0 + ch) * NSTATE + ln + 16]) * LOG2E;
  const float Dd = Dpar[d0 + dd];  // store role
  const size_t segbase = (size_t)b * L_SEQ;
  const int bccol = (nb & 15) * 4 + (nb >> 4) * 2;

  float uu[4];
  {  // prologue: stage chunk 0
#pragma unroll
    for (int k = 0; k < 4; ++k) {
      const size_t rX = (segbase + tl + 16 * k) * DINNER + d0 + dd;
      const float dv = dy[rX];
      const float uv = x[rX];
      *(float2*)&sDU[0][dd][((tl >> 1) + 8 * k) * 4 + (tl & 1) * 2] =
          make_float2(dv, dv * uv);
      uu[k] = uv;
    }
#pragma unroll
    for (int k = 0; k < 8; ++k) {
      const int t = tq + 8 * k;
      const size_t rB = (segbase + t) * 128 + 64 + nb;
      *(float2*)&sBCp[0][t][bccol] = make_float2(dbc[rB], dbc[rB + 32]);
    }
  }
  __syncthreads();

  f32x2 h = (f32x2)(0.f);
  for (int c = 0; c < NCHK; ++c) {
    const int cb = c & 1;
    float dn[4], un[4];
    float2 bcx[8];
#pragma unroll
    for (int k = 0; k < 4; ++k) dn[k] = un[k] = 0.f;
#pragma unroll
    for (int k = 0; k < 8; ++k) bcx[k] = make_float2(0.f, 0.f);
    if (c < NCHK - 1) {  // prefetch next chunk (hidden under compute)
#pragma unroll
      for (int k = 0; k < 4; ++k) {
        const size_t rX = (segbase + (c + 1) * TCH + tl + 16 * k) * DINNER + d0 + dd;
        dn[k] = dy[rX];
        un[k] = x[rX];
      }
#pragma unroll
      for (int k = 0; k < 8; ++k) {
        const size_t rB = (segbase + (c + 1) * TCH + tq + 8 * k) * 128 + 64 + nb;
        bcx[k] = make_float2(dbc[rB], dbc[rB + 32]);
      }
    }

    const float* pDU = &sDU[cb][ch][0];
    const float* pBC = &sBCp[cb][0][ln * 4];
    float yv[4] = {0.f, 0.f, 0.f, 0.f};
#pragma unroll
    for (int t2 = 0; t2 < TCH / 2; ++t2) {
      const float4 du = *(const float4*)(pDU + t2 * 4);
      const float4 b0 = *(const float4*)(pBC + (2 * t2) * 68);
      const float4 b1 = *(const float4*)(pBC + (2 * t2 + 1) * 68);
      {
        const int t = 2 * t2;
        f32x2 ea = An2 * du.x;
        f32x2 dA;
        dA.x = EXP2(ea.x);
        dA.y = EXP2(ea.y);
        f32x2 Bp;
        Bp.x = b0.x;
        Bp.y = b0.z;
        f32x2 Cp;
        Cp.x = b0.y;
        Cp.y = b0.w;
        h = dA * h + Bp * du.y;
        const f32x2 pp = h * Cp;
        const float p = red16(pp.x + pp.y);
        yv[t >> 4] = (ln == (t & 15)) ? p : yv[t >> 4];
      }
      {
        const int t = 2 * t2 + 1;
        f32x2 ea = An2 * du.z;
        f32x2 dA;
        dA.x = EXP2(ea.x);
        dA.y = EXP2(ea.y);
        f32x2 Bp;
        Bp.x = b1.x;
        Bp.y = b1.z;
        f32x2 Cp;
        Cp.x = b1.y;
        Cp.y = b1.w;
        h = dA * h + Bp * du.w;
        const f32x2 pp = h * Cp;
        const float p = red16(pp.x + pp.y);
        yv[t >> 4] = (ln == (t & 15)) ? p : yv[t >> 4];
      }
    }
#pragma unroll
    for (int k = 0; k < 4; ++k) sY[cb][ln + 16 * k][ch] = yv[k];

    if (c < NCHK - 1) {  // stage next chunk into other buffer
#pragma unroll
      for (int k = 0; k < 4; ++k)
        *(float2*)&sDU[cb ^ 1][dd][((tl >> 1) + 8 * k) * 4 + (tl & 1) * 2] =
            make_float2(dn[k], dn[k] * un[k]);
#pragma unroll
      for (int k = 0; k < 8; ++k)
        *(float2*)&sBCp[cb ^ 1][tq + 8 * k][bccol] = bcx[k];
    }
    __syncthreads();  // single barrier per 64-t chunk

#pragma unroll
    for (int k = 0; k < 4; ++k) {
      dy[(segbase + c * TCH + tl + 16 * k) * DINNER + d0 + dd] =
          fmaf(uu[k], Dd, sY[cb][tl + 16 * k][dd]);
      uu[k] = un[k];
    }
  }
}

extern "C" void kernel_launch(void* const* d_in, const int* in_sizes, int n_in,
                              void* d_out, int out_size, void* d_ws, size_t ws_size,
                              hipStream_t stream) {
  const float* x    = (const float*)d_in[0];
  const float* Wbc  = (const float*)d_in[2];
  const float* Wdt  = (const float*)d_in[3];
  const float* bdt  = (const float*)d_in[4];
  const float* Alog = (const float*)d_in[5];
  const float* Dpar = (const float*)d_in[6];
  float* dy  = (float*)d_out;
  float* dbc = (float*)d_ws;  // 4 MiB

  const size_t DBC_BYTES = (size_t)NROWS * 128 * 4;               // 4 MiB
  const size_t WCONV_BYTES = (size_t)(WBC_ELEMS + WDT_ELEMS) * 2; // 768 KiB

  const bool mfma_ok = ws_size >= DBC_BYTES + WCONV_BYTES;

  if (mfma_ok) {
    unsigned short* Wb = (unsigned short*)((char*)d_ws + DBC_BYTES);
    unsigned short* Wd = Wb + WBC_ELEMS;
    hipLaunchKernelGGL(k_conv, dim3((WBC_ELEMS + WDT_ELEMS) / 256), dim3(256), 0,
                       stream, Wbc, Wdt, Wb);
    hipLaunchKernelGGL(k_dbc_mfma, dim3(NROWS / 32), dim3(512), 0, stream,
                       x, Wb, dbc);
    hipLaunchKernelGGL(k_dt_mfma, dim3(DINNER / 256, NROWS / 32), dim3(256), 0,
                       stream, dbc, Wd, bdt, dy);
  } else {
    hipLaunchKernelGGL(k_dbc, dim3(NROWS / 32), dim3(256), 0, stream, x, Wbc, dbc);
    hipLaunchKernelGGL(k_dt, dim3(DINNER / 128, NROWS / 16), dim3(256), 0, stream,
                       dbc, Wdt, bdt, dy);
  }

  // monolithic packed scan: 256-thr blocks, 16 ch x 16 lanes, TCH=64
  hipLaunchKernelGGL(k_scanp, dim3(BSZ * DINNER / 16), dim3(256), 0, stream,
                     x, dbc, Alog, Dpar, dy);
}